// Round 12
// baseline (50.583 us; speedup 1.0000x reference)
//
#include <hip/hip_runtime.h>

constexpr int NC = 16;        // n_cgs
constexpr int NP = 256;       // npair
constexpr int PITCH = 264;    // LDS row pitch (floats)
constexpr int NATOMS = 512;
constexpr int NB = 128;
constexpr int WROW = NP + NP * NP;  // 65792 floats per W row
constexpr int ANP = 21;       // an LDS pitch (21 coprime 32)
constexpr int DXP = 5;        // dx LDS pitch (5 coprime 32)

#define F4ADD(a, v) do { (a).x += (v).x; (a).y += (v).y; (a).z += (v).z; (a).w += (v).w; } while (0)
#define F4SUB(a, v) do { (a).x -= (v).x; (a).y -= (v).y; (a).z -= (v).z; (a).w -= (v).w; } while (0)

// ---------------------------------------------------------------------------
// Kernel A: R7-exact dwordx4 deep-stream of W2 (best measured: 44.7 total).
// One block per atom; wave s owns rows [64s,64s+64), lane l cols [4l,4l+4).
// 64 fully-unrolled float4 loads/thread (1 KB contiguous per wave instr).
//   h4[d] += row (d = i&15);  hn4[g] += row (p>>4 = 4s+g)
// Single barrier -> combine 4 wave planes -> q-fold -> wcd[n][d*16+c].
// sa/xyz copies moved OUT (to k_recon2) — k_stream reads only W.
// ---------------------------------------------------------------------------
__global__ __launch_bounds__(256) void k_stream(const float* __restrict__ W,
                                                float* __restrict__ wcd,
                                                float* __restrict__ w1c) {
    __shared__ float Hp[4][NC][PITCH];   // 67.6 KB -> 2 blocks/CU
    const int n = blockIdx.x;
    const int t = threadIdx.x;
    const int s = t >> 6;    // wave: rows [64s, 64s+64)
    const int l = t & 63;    // cols [4l, 4l+4)

    // w1c (L2-hot 1 KB row head)
    if (t < NC) {
        const float* __restrict__ W1 = W + (size_t)n * WROW;
        float a1 = 0.f;
#pragma unroll
        for (int pi = 0; pi < NC; ++pi) a1 += W1[pi * NC + t];
#pragma unroll
        for (int pj = 0; pj < NC; ++pj) a1 -= W1[t * NC + pj];
        w1c[n * NC + t] = a1;
    }

    // ---- stream 64 rows x 4 cols as float4 (fully unrolled) ----
    const float4* __restrict__ wp =
        (const float4*)W + ((size_t)n * 16448 + 64 + (size_t)(s * 64) * 64 + l);
    float4 h4[NC], hn4[4];
#pragma unroll
    for (int d = 0; d < NC; ++d) { h4[d].x = 0.f; h4[d].y = 0.f; h4[d].z = 0.f; h4[d].w = 0.f; }
#pragma unroll
    for (int g = 0; g < 4; ++g) { hn4[g].x = 0.f; hn4[g].y = 0.f; hn4[g].z = 0.f; hn4[g].w = 0.f; }
#pragma unroll
    for (int i = 0; i < 64; ++i) {
        const float4 v = wp[(size_t)i * 64];
        F4ADD(h4[i & 15], v);
        F4ADD(hn4[i >> 4], v);
    }
    // fold -delta(d, p>>4): p>>4 = 4s+g
    switch (s) {
      case 0:
#pragma unroll
        for (int k = 0; k < 4; ++k) F4SUB(h4[k], hn4[k]);
        break;
      case 1:
#pragma unroll
        for (int k = 0; k < 4; ++k) F4SUB(h4[4 + k], hn4[k]);
        break;
      case 2:
#pragma unroll
        for (int k = 0; k < 4; ++k) F4SUB(h4[8 + k], hn4[k]);
        break;
      default:
#pragma unroll
        for (int k = 0; k < 4; ++k) F4SUB(h4[12 + k], hn4[k]);
        break;
    }
    // per-wave H plane -> LDS (16-B contiguous per lane: conflict-free)
#pragma unroll
    for (int d = 0; d < NC; ++d) {
        *(float4*)(&Hp[s][d][4 * l]) = h4[d];
    }
    __syncthreads();

    // combine 4 planes into plane 0 (consecutive t: conflict-free)
#pragma unroll
    for (int d = 0; d < NC; ++d) {
        Hp[0][d][t] += (Hp[1][d][t] + Hp[2][d][t]) + Hp[3][d][t];
    }
    __syncthreads();

    // q-fold (R5/R6/R7-verified): t -> (d = t>>4, c = t&15), coalesced store
    {
        const int d = t >> 4, c = t & 15;
        float rp = 0.f, rm = 0.f;
#pragma unroll
        for (int qi = 0; qi < NC; ++qi) rp += Hp[0][d][qi * NC + c];
#pragma unroll
        for (int qj = 0; qj < NC; ++qj) rm += Hp[0][d][c * NC + qj];
        wcd[n * NP + t] = rp - rm;
    }
}

// ---------------------------------------------------------------------------
// Kernel B: fused reconstruction.  grid = 128 batches, 512 threads (1/atom).
// Absorbs sa/xyz output copies; computes dx in-block (R1-verified loop over
// L2-hot wcd rows), cgo via R6-verified j-split, then final output.
// No dxp round-trip, one launch gap saved.
// ---------------------------------------------------------------------------
__global__ __launch_bounds__(512) void k_recon2(const float* __restrict__ cg_xyz,
                                                const float* __restrict__ assign_norm,
                                                const int* __restrict__ assign_idx,
                                                const float* __restrict__ wcd,
                                                const float* __restrict__ w1c,
                                                const float* __restrict__ soft_assign,
                                                const float* __restrict__ xyz,
                                                float* __restrict__ out_sa,
                                                float* __restrict__ out_xyz,
                                                float* __restrict__ out_recon) {
    __shared__ float an_l[NATOMS][ANP];   // 43.0 KB
    __shared__ float dxl[NATOMS][DXP];    // 10.2 KB
    __shared__ float xs[NC][4];
    __shared__ float cxs[NP][4];          // 4 KB
    __shared__ float cgo_l[NC][4];
    const int b = blockIdx.x;
    const int t = threadIdx.x;

    // absorbed output copies (4 float4 sa + <=1 float4 xyz per thread)
#pragma unroll
    for (int k = 0; k < 4; ++k) {
        ((float4*)out_sa)[b * 2048 + k * 512 + t] =
            ((const float4*)soft_assign)[b * 2048 + k * 512 + t];
    }
    if (t < 384) {
        ((float4*)out_xyz)[b * 384 + t] = ((const float4*)xyz)[b * 384 + t];
    }

    // an -> LDS (coalesced float4 reads; b32 writes conflict-free: 21 coprime 32)
    {
        const float4* __restrict__ anr =
            (const float4*)(assign_norm + ((size_t)b * NATOMS + t) * NC);
#pragma unroll
        for (int i = 0; i < 4; ++i) {
            const float4 v = anr[i];
            an_l[t][4 * i + 0] = v.x; an_l[t][4 * i + 1] = v.y;
            an_l[t][4 * i + 2] = v.z; an_l[t][4 * i + 3] = v.w;
        }
    }
    if (t < 48) xs[t / 3][t % 3] = cg_xyz[(size_t)b * NC * 3 + t];
    __syncthreads();

    // cross table (broadcast-read, conflict-free)
    if (t < NP) {
        const int c = t & 15, d = t >> 4;
        const float ax = xs[c][0], ay = xs[c][1], az = xs[c][2];
        const float bx = xs[d][0], by = xs[d][1], bz = xs[d][2];
        cxs[t][0] = ay * bz - az * by;
        cxs[t][1] = az * bx - ax * bz;
        cxs[t][2] = ax * by - ay * bx;
        cxs[t][3] = 0.f;
    }
    __syncthreads();

    // dx for atom t (wcd row t: 1 KB from L2/L3, shared across all 128 blocks)
    float dx0 = 0.f, dx1 = 0.f, dx2 = 0.f;
    {
        const float4* __restrict__ wrow = (const float4*)(wcd + t * NP);
#pragma unroll 8
        for (int k4 = 0; k4 < 64; ++k4) {
            const float4 w = wrow[k4];
            const float4 c0 = *(const float4*)(&cxs[k4 * 4 + 0][0]);
            const float4 c1 = *(const float4*)(&cxs[k4 * 4 + 1][0]);
            const float4 c2 = *(const float4*)(&cxs[k4 * 4 + 2][0]);
            const float4 c3 = *(const float4*)(&cxs[k4 * 4 + 3][0]);
            dx0 += w.x * c0.x + w.y * c1.x + w.z * c2.x + w.w * c3.x;
            dx1 += w.x * c0.y + w.y * c1.y + w.z * c2.y + w.w * c3.y;
            dx2 += w.x * c0.z + w.y * c1.z + w.z * c2.z + w.w * c3.z;
        }
        const float* __restrict__ w1row = w1c + t * NC;
#pragma unroll
        for (int c = 0; c < NC; ++c) {
            const float wv = w1row[c];
            dx0 += wv * xs[c][0]; dx1 += wv * xs[c][1]; dx2 += wv * xs[c][2];
        }
    }
    dxl[t][0] = dx0; dxl[t][1] = dx1; dxl[t][2] = dx2;
    __syncthreads();

    // cgo[j] = sum_i an[i][j]*dx[i]: thread (j = t>>5, g = t&31), atoms g+32k
    {
        const int j = t >> 5, g = t & 31;
        float p0 = 0.f, p1 = 0.f, p2 = 0.f;
#pragma unroll
        for (int k = 0; k < 16; ++k) {
            const int i = g + 32 * k;
            const float a = an_l[i][j];
            p0 += a * dxl[i][0];
            p1 += a * dxl[i][1];
            p2 += a * dxl[i][2];
        }
#pragma unroll
        for (int sh = 1; sh < 32; sh <<= 1) {
            p0 += __shfl_xor(p0, sh);
            p1 += __shfl_xor(p1, sh);
            p2 += __shfl_xor(p2, sh);
        }
        if (g == 0) { cgo_l[j][0] = p0; cgo_l[j][1] = p1; cgo_l[j][2] = p2; }
    }
    __syncthreads();

    const int ci = assign_idx[t];
    const float r0 = xs[ci][0] - cgo_l[ci][0] + dx0;
    const float r1 = xs[ci][1] - cgo_l[ci][1] + dx1;
    const float r2 = xs[ci][2] - cgo_l[ci][2] + dx2;
    const size_t ob = ((size_t)b * NATOMS + t) * 3;
    out_recon[ob + 0] = r0;
    out_recon[ob + 1] = r1;
    out_recon[ob + 2] = r2;
}

extern "C" void kernel_launch(void* const* d_in, const int* in_sizes, int n_in,
                              void* d_out, int out_size, void* d_ws, size_t ws_size,
                              hipStream_t stream) {
    (void)in_sizes; (void)n_in; (void)out_size; (void)ws_size;
    const float* soft_assign = (const float*)d_in[0];
    const float* xyz         = (const float*)d_in[1];
    const float* cg_xyz      = (const float*)d_in[2];
    const float* assign_norm = (const float*)d_in[3];
    const float* W           = (const float*)d_in[4];
    const int*   assign_idx  = (const int*)d_in[5];

    float* out       = (float*)d_out;
    float* out_sa    = out;                                   // 128*512*16
    float* out_xyz   = out + (size_t)NB * NATOMS * NC;        // 128*512*3
    float* out_recon = out_xyz + (size_t)NB * NATOMS * 3;

    float* wcd = (float*)d_ws;                                // 512*256
    float* w1c = wcd + (size_t)NATOMS * NP;                   // 512*16

    k_stream<<<dim3(NATOMS), dim3(256), 0, stream>>>(W, wcd, w1c);
    k_recon2<<<dim3(NB), dim3(512), 0, stream>>>(cg_xyz, assign_norm, assign_idx,
                                                 wcd, w1c, soft_assign, xyz,
                                                 out_sa, out_xyz, out_recon);
}

// Round 13
// 49.818 us; speedup vs baseline: 1.0153x; 1.0153x over previous
//
#include <hip/hip_runtime.h>

constexpr int NC = 16;        // n_cgs
constexpr int NP = 256;       // npair
constexpr int PITCH = 264;    // LDS row pitch (floats)
constexpr int NATOMS = 512;
constexpr int NB = 128;
constexpr int WROW = NP + NP * NP;  // 65792 floats per W row
constexpr int ANP = 21;       // an LDS pitch (21 coprime 32)
constexpr int DXP = 5;        // dx LDS pitch (5 coprime 32)

#define F4ADD(a, v) do { (a).x += (v).x; (a).y += (v).y; (a).z += (v).z; (a).w += (v).w; } while (0)
#define F4SUB(a, v) do { (a).x -= (v).x; (a).y -= (v).y; (a).z -= (v).z; (a).w -= (v).w; } while (0)

// ---------------------------------------------------------------------------
// Kernel A: R7-EXACT dwordx4 deep-stream of W2 (best measured config).
// One block per atom; wave s owns rows [64s,64s+64), lane l cols [4l,4l+4).
// 64 fully-unrolled float4 loads/thread (1 KB contiguous per wave instr).
//   h4[d] += row (d = i&15);  hn4[g] += row (p>>4 = 4s+g)
// Single barrier -> combine 4 wave planes -> q-fold -> wcd[n][d*16+c].
// Absorbs sa/xyz output copies and w1c (R7 placement — verified fastest).
// ---------------------------------------------------------------------------
__global__ __launch_bounds__(256) void k_stream(const float* __restrict__ W,
                                                const float* __restrict__ soft_assign,
                                                const float* __restrict__ xyz,
                                                float* __restrict__ wcd,
                                                float* __restrict__ w1c,
                                                float* __restrict__ out_sa,
                                                float* __restrict__ out_xyz) {
    __shared__ float Hp[4][NC][PITCH];   // 67.6 KB -> 2 blocks/CU
    const int n = blockIdx.x;
    const int t = threadIdx.x;
    const int s = t >> 6;    // wave: rows [64s, 64s+64)
    const int l = t & 63;    // cols [4l, 4l+4)

    // absorbed output copies (2 float4 sa + 96 float4 xyz per block)
    ((float4*)out_sa)[n * 512 + t]       = ((const float4*)soft_assign)[n * 512 + t];
    ((float4*)out_sa)[n * 512 + 256 + t] = ((const float4*)soft_assign)[n * 512 + 256 + t];
    if (t < 96) {
        ((float4*)out_xyz)[n * 96 + t] = ((const float4*)xyz)[n * 96 + t];
    }
    // w1c (L2-hot 1 KB row head)
    if (t < NC) {
        const float* __restrict__ W1 = W + (size_t)n * WROW;
        float a1 = 0.f;
#pragma unroll
        for (int pi = 0; pi < NC; ++pi) a1 += W1[pi * NC + t];
#pragma unroll
        for (int pj = 0; pj < NC; ++pj) a1 -= W1[t * NC + pj];
        w1c[n * NC + t] = a1;
    }

    // ---- stream 64 rows x 4 cols as float4 (fully unrolled) ----
    const float4* __restrict__ wp =
        (const float4*)W + ((size_t)n * 16448 + 64 + (size_t)(s * 64) * 64 + l);
    float4 h4[NC], hn4[4];
#pragma unroll
    for (int d = 0; d < NC; ++d) { h4[d].x = 0.f; h4[d].y = 0.f; h4[d].z = 0.f; h4[d].w = 0.f; }
#pragma unroll
    for (int g = 0; g < 4; ++g) { hn4[g].x = 0.f; hn4[g].y = 0.f; hn4[g].z = 0.f; hn4[g].w = 0.f; }
#pragma unroll
    for (int i = 0; i < 64; ++i) {
        const float4 v = wp[(size_t)i * 64];
        F4ADD(h4[i & 15], v);
        F4ADD(hn4[i >> 4], v);
    }
    // fold -delta(d, p>>4): p>>4 = 4s+g
    switch (s) {
      case 0:
#pragma unroll
        for (int k = 0; k < 4; ++k) F4SUB(h4[k], hn4[k]);
        break;
      case 1:
#pragma unroll
        for (int k = 0; k < 4; ++k) F4SUB(h4[4 + k], hn4[k]);
        break;
      case 2:
#pragma unroll
        for (int k = 0; k < 4; ++k) F4SUB(h4[8 + k], hn4[k]);
        break;
      default:
#pragma unroll
        for (int k = 0; k < 4; ++k) F4SUB(h4[12 + k], hn4[k]);
        break;
    }
    // per-wave H plane -> LDS (16-B contiguous per lane: conflict-free)
#pragma unroll
    for (int d = 0; d < NC; ++d) {
        *(float4*)(&Hp[s][d][4 * l]) = h4[d];
    }
    __syncthreads();

    // combine 4 planes into plane 0 (consecutive t: conflict-free)
#pragma unroll
    for (int d = 0; d < NC; ++d) {
        Hp[0][d][t] += (Hp[1][d][t] + Hp[2][d][t]) + Hp[3][d][t];
    }
    __syncthreads();

    // q-fold (R5/R6/R7-verified): t -> (d = t>>4, c = t&15), coalesced store
    {
        const int d = t >> 4, c = t & 15;
        float rp = 0.f, rm = 0.f;
#pragma unroll
        for (int qi = 0; qi < NC; ++qi) rp += Hp[0][d][qi * NC + c];
#pragma unroll
        for (int qj = 0; qj < NC; ++qj) rm += Hp[0][d][c * NC + qj];
        wcd[n * NP + t] = rp - rm;
    }
}

// ---------------------------------------------------------------------------
// Kernel B: fused reconstruction (R12's fusion, WITHOUT the copies).
// grid = 128 batches, 512 threads (one per atom).  dx from L2-hot wcd rows,
// cgo via j-split reduction, final output.  No dxp round-trip.
// ---------------------------------------------------------------------------
__global__ __launch_bounds__(512) void k_recon2(const float* __restrict__ cg_xyz,
                                                const float* __restrict__ assign_norm,
                                                const int* __restrict__ assign_idx,
                                                const float* __restrict__ wcd,
                                                const float* __restrict__ w1c,
                                                float* __restrict__ out_recon) {
    __shared__ float an_l[NATOMS][ANP];   // 43.0 KB
    __shared__ float dxl[NATOMS][DXP];    // 10.2 KB
    __shared__ float xs[NC][4];
    __shared__ float cxs[NP][4];          // 4 KB
    __shared__ float cgo_l[NC][4];
    const int b = blockIdx.x;
    const int t = threadIdx.x;

    // an -> LDS (coalesced float4 reads; b32 writes conflict-free: 21 coprime 32)
    {
        const float4* __restrict__ anr =
            (const float4*)(assign_norm + ((size_t)b * NATOMS + t) * NC);
#pragma unroll
        for (int i = 0; i < 4; ++i) {
            const float4 v = anr[i];
            an_l[t][4 * i + 0] = v.x; an_l[t][4 * i + 1] = v.y;
            an_l[t][4 * i + 2] = v.z; an_l[t][4 * i + 3] = v.w;
        }
    }
    if (t < 48) xs[t / 3][t % 3] = cg_xyz[(size_t)b * NC * 3 + t];
    __syncthreads();

    // cross table (broadcast-read, conflict-free)
    if (t < NP) {
        const int c = t & 15, d = t >> 4;
        const float ax = xs[c][0], ay = xs[c][1], az = xs[c][2];
        const float bx = xs[d][0], by = xs[d][1], bz = xs[d][2];
        cxs[t][0] = ay * bz - az * by;
        cxs[t][1] = az * bx - ax * bz;
        cxs[t][2] = ax * by - ay * bx;
        cxs[t][3] = 0.f;
    }
    __syncthreads();

    // dx for atom t (wcd row t: 1 KB from L2/L3, shared across all 128 blocks)
    float dx0 = 0.f, dx1 = 0.f, dx2 = 0.f;
    {
        const float4* __restrict__ wrow = (const float4*)(wcd + t * NP);
#pragma unroll 8
        for (int k4 = 0; k4 < 64; ++k4) {
            const float4 w = wrow[k4];
            const float4 c0 = *(const float4*)(&cxs[k4 * 4 + 0][0]);
            const float4 c1 = *(const float4*)(&cxs[k4 * 4 + 1][0]);
            const float4 c2 = *(const float4*)(&cxs[k4 * 4 + 2][0]);
            const float4 c3 = *(const float4*)(&cxs[k4 * 4 + 3][0]);
            dx0 += w.x * c0.x + w.y * c1.x + w.z * c2.x + w.w * c3.x;
            dx1 += w.x * c0.y + w.y * c1.y + w.z * c2.y + w.w * c3.y;
            dx2 += w.x * c0.z + w.y * c1.z + w.z * c2.z + w.w * c3.z;
        }
        const float* __restrict__ w1row = w1c + t * NC;
#pragma unroll
        for (int c = 0; c < NC; ++c) {
            const float wv = w1row[c];
            dx0 += wv * xs[c][0]; dx1 += wv * xs[c][1]; dx2 += wv * xs[c][2];
        }
    }
    dxl[t][0] = dx0; dxl[t][1] = dx1; dxl[t][2] = dx2;
    __syncthreads();

    // cgo[j] = sum_i an[i][j]*dx[i]: thread (j = t>>5, g = t&31), atoms g+32k
    {
        const int j = t >> 5, g = t & 31;
        float p0 = 0.f, p1 = 0.f, p2 = 0.f;
#pragma unroll
        for (int k = 0; k < 16; ++k) {
            const int i = g + 32 * k;
            const float a = an_l[i][j];
            p0 += a * dxl[i][0];
            p1 += a * dxl[i][1];
            p2 += a * dxl[i][2];
        }
#pragma unroll
        for (int sh = 1; sh < 32; sh <<= 1) {
            p0 += __shfl_xor(p0, sh);
            p1 += __shfl_xor(p1, sh);
            p2 += __shfl_xor(p2, sh);
        }
        if (g == 0) { cgo_l[j][0] = p0; cgo_l[j][1] = p1; cgo_l[j][2] = p2; }
    }
    __syncthreads();

    const int ci = assign_idx[t];
    const float r0 = xs[ci][0] - cgo_l[ci][0] + dx0;
    const float r1 = xs[ci][1] - cgo_l[ci][1] + dx1;
    const float r2 = xs[ci][2] - cgo_l[ci][2] + dx2;
    const size_t ob = ((size_t)b * NATOMS + t) * 3;
    out_recon[ob + 0] = r0;
    out_recon[ob + 1] = r1;
    out_recon[ob + 2] = r2;
}

extern "C" void kernel_launch(void* const* d_in, const int* in_sizes, int n_in,
                              void* d_out, int out_size, void* d_ws, size_t ws_size,
                              hipStream_t stream) {
    (void)in_sizes; (void)n_in; (void)out_size; (void)ws_size;
    const float* soft_assign = (const float*)d_in[0];
    const float* xyz         = (const float*)d_in[1];
    const float* cg_xyz      = (const float*)d_in[2];
    const float* assign_norm = (const float*)d_in[3];
    const float* W           = (const float*)d_in[4];
    const int*   assign_idx  = (const int*)d_in[5];

    float* out       = (float*)d_out;
    float* out_sa    = out;                                   // 128*512*16
    float* out_xyz   = out + (size_t)NB * NATOMS * NC;        // 128*512*3
    float* out_recon = out_xyz + (size_t)NB * NATOMS * 3;

    float* wcd = (float*)d_ws;                                // 512*256
    float* w1c = wcd + (size_t)NATOMS * NP;                   // 512*16

    k_stream<<<dim3(NATOMS), dim3(256), 0, stream>>>(W, soft_assign, xyz,
                                                     wcd, w1c, out_sa, out_xyz);
    k_recon2<<<dim3(NB), dim3(512), 0, stream>>>(cg_xyz, assign_norm, assign_idx,
                                                 wcd, w1c, out_recon);
}

// Round 14
// 44.908 us; speedup vs baseline: 1.1264x; 1.1094x over previous
//
#include <hip/hip_runtime.h>

constexpr int NC = 16;        // n_cgs
constexpr int NP = 256;       // npair
constexpr int PITCH = 264;    // LDS row pitch (floats)
constexpr int NATOMS = 512;
constexpr int NB = 128;
constexpr int WROW = NP + NP * NP;  // 65792 floats per W row
constexpr int ANP = 21;       // an LDS pitch (21 coprime 32)
constexpr int DXP = 5;        // dx LDS pitch (5 coprime 32)

#define F4ADD(a, v) do { (a).x += (v).x; (a).y += (v).y; (a).z += (v).z; (a).w += (v).w; } while (0)
#define F4SUB(a, v) do { (a).x -= (v).x; (a).y -= (v).y; (a).z -= (v).z; (a).w -= (v).w; } while (0)

// ---------------------------------------------------------------------------
// Kernel A: dwordx4 deep-stream of W2.  One block per atom; wave s owns rows
// [64s, 64s+64), lane l owns cols [4l, 4l+4).  64 float4 loads per thread,
// fully unrolled: every wave instruction reads a contiguous 1 KB row.
//   h4[d] += row (d = i&15);  hn4[g] += row (g = i>>4, p>>4 = 4s+g)
// Barrier -> combine 4 wave-partial H planes (conflict-free) -> q-fold
// -> wcd[n][d*16+c].  Absorbs sa/xyz copies and w1c.   [R7: best measured]
// ---------------------------------------------------------------------------
__global__ __launch_bounds__(256) void k_stream(const float* __restrict__ W,
                                                const float* __restrict__ soft_assign,
                                                const float* __restrict__ xyz,
                                                float* __restrict__ wcd,
                                                float* __restrict__ w1c,
                                                float* __restrict__ out_sa,
                                                float* __restrict__ out_xyz) {
    __shared__ float Hp[4][NC][PITCH];   // 67.6 KB -> 2 blocks/CU
    const int n = blockIdx.x;
    const int t = threadIdx.x;
    const int s = t >> 6;    // wave: rows [64s, 64s+64)
    const int l = t & 63;    // cols [4l, 4l+4)

    // absorbed output copies (2 float4 sa + 96 float4 xyz per block)
    ((float4*)out_sa)[n * 512 + t]       = ((const float4*)soft_assign)[n * 512 + t];
    ((float4*)out_sa)[n * 512 + 256 + t] = ((const float4*)soft_assign)[n * 512 + 256 + t];
    if (t < 96) {
        ((float4*)out_xyz)[n * 96 + t] = ((const float4*)xyz)[n * 96 + t];
    }
    // w1c (L2-hot 1 KB row head)
    if (t < NC) {
        const float* __restrict__ W1 = W + (size_t)n * WROW;
        float a1 = 0.f;
#pragma unroll
        for (int pi = 0; pi < NC; ++pi) a1 += W1[pi * NC + t];
#pragma unroll
        for (int pj = 0; pj < NC; ++pj) a1 -= W1[t * NC + pj];
        w1c[n * NC + t] = a1;
    }

    // ---- stream 64 rows x 4 cols as float4 ----
    const float4* __restrict__ wp =
        (const float4*)W + ((size_t)n * 16448 + 64 + (size_t)(s * 64) * 64 + l);
    float4 h4[NC], hn4[4];
#pragma unroll
    for (int d = 0; d < NC; ++d) { h4[d].x = 0.f; h4[d].y = 0.f; h4[d].z = 0.f; h4[d].w = 0.f; }
#pragma unroll
    for (int g = 0; g < 4; ++g) { hn4[g].x = 0.f; hn4[g].y = 0.f; hn4[g].z = 0.f; hn4[g].w = 0.f; }
#pragma unroll
    for (int i = 0; i < 64; ++i) {
        const float4 v = wp[(size_t)i * 64];
        F4ADD(h4[i & 15], v);
        F4ADD(hn4[i >> 4], v);
    }
    // fold -delta(d, p>>4): p>>4 = 4s+g
    switch (s) {
      case 0:
#pragma unroll
        for (int k = 0; k < 4; ++k) F4SUB(h4[k], hn4[k]);
        break;
      case 1:
#pragma unroll
        for (int k = 0; k < 4; ++k) F4SUB(h4[4 + k], hn4[k]);
        break;
      case 2:
#pragma unroll
        for (int k = 0; k < 4; ++k) F4SUB(h4[8 + k], hn4[k]);
        break;
      default:
#pragma unroll
        for (int k = 0; k < 4; ++k) F4SUB(h4[12 + k], hn4[k]);
        break;
    }
    // per-wave H plane -> LDS (16-B contiguous per lane: conflict-free)
#pragma unroll
    for (int d = 0; d < NC; ++d) {
        *(float4*)(&Hp[s][d][4 * l]) = h4[d];
    }
    __syncthreads();

    // combine 4 planes into plane 0 (consecutive t: conflict-free)
#pragma unroll
    for (int d = 0; d < NC; ++d) {
        Hp[0][d][t] += (Hp[1][d][t] + Hp[2][d][t]) + Hp[3][d][t];
    }
    __syncthreads();

    // q-fold: t -> (d = t>>4, c = t&15), coalesced store
    {
        const int d = t >> 4, c = t & 15;
        float rp = 0.f, rm = 0.f;
#pragma unroll
        for (int qi = 0; qi < NC; ++qi) rp += Hp[0][d][qi * NC + c];
#pragma unroll
        for (int qj = 0; qj < NC; ++qj) rm += Hp[0][d][c * NC + qj];
        wcd[n * NP + t] = rp - rm;
    }
}

// ---------------------------------------------------------------------------
// Kernel B: dx partials.  grid = 128 batches x 4 m-quarters, 256 threads.
// ---------------------------------------------------------------------------
__global__ __launch_bounds__(256) void k_dx(const float* __restrict__ cg_xyz,
                                            const float* __restrict__ wcd,
                                            const float* __restrict__ w1c,
                                            float* __restrict__ dxp) {
    __shared__ float xs[NC][4];
    __shared__ float cxs[64][4];
    const int b = blockIdx.x >> 2;
    const int q = blockIdx.x & 3;
    const int t = threadIdx.x;

    if (t < 48) xs[t / 3][t % 3] = cg_xyz[(size_t)b * NC * 3 + t];
    __syncthreads();
    if (t < 64) {
        const int m = q * 64 + t, c = m & 15, d = m >> 4;
        const float ax = xs[c][0], ay = xs[c][1], az = xs[c][2];
        const float bx = xs[d][0], by = xs[d][1], bz = xs[d][2];
        cxs[t][0] = ay * bz - az * by;
        cxs[t][1] = az * bx - ax * bz;
        cxs[t][2] = ax * by - ay * bx;
        cxs[t][3] = 0.f;
    }
    __syncthreads();

#pragma unroll
    for (int a = 0; a < 2; ++a) {
        const int n = a * 256 + t;
        const float4* __restrict__ w0 =
            (const float4*)(wcd + (size_t)n * NP + q * 64);
        float dx0 = 0.f, dx1 = 0.f, dx2 = 0.f;
#pragma unroll
        for (int k4 = 0; k4 < 16; ++k4) {
            const float4 w = w0[k4];
            const float4 c0 = *(const float4*)(&cxs[k4 * 4 + 0][0]);
            const float4 c1 = *(const float4*)(&cxs[k4 * 4 + 1][0]);
            const float4 c2 = *(const float4*)(&cxs[k4 * 4 + 2][0]);
            const float4 c3 = *(const float4*)(&cxs[k4 * 4 + 3][0]);
            dx0 += w.x * c0.x + w.y * c1.x + w.z * c2.x + w.w * c3.x;
            dx1 += w.x * c0.y + w.y * c1.y + w.z * c2.y + w.w * c3.y;
            dx2 += w.x * c0.z + w.y * c1.z + w.z * c2.z + w.w * c3.z;
        }
        if (q == 0) {
            const float* __restrict__ w1r = w1c + n * NC;
#pragma unroll
            for (int c = 0; c < NC; ++c) {
                const float wv = w1r[c];
                dx0 += wv * xs[c][0]; dx1 += wv * xs[c][1]; dx2 += wv * xs[c][2];
            }
        }
        float* __restrict__ op = dxp + (((size_t)q * NB + b) * NATOMS + n) * 3;
        op[0] = dx0; op[1] = dx1; op[2] = dx2;
    }
}

// ---------------------------------------------------------------------------
// Kernel C: finish.  grid = 128 batches, 512 threads (one per atom).
// ---------------------------------------------------------------------------
__global__ __launch_bounds__(512) void k_finish(const float* __restrict__ cg_xyz,
                                                const float* __restrict__ assign_norm,
                                                const int* __restrict__ assign_idx,
                                                const float* __restrict__ dxp,
                                                float* __restrict__ out_recon) {
    __shared__ float an_l[NATOMS][ANP];   // 43.0 KB
    __shared__ float dxl[NATOMS][DXP];    // 10.2 KB
    __shared__ float xs[NC][4];
    __shared__ float cgo_l[NC][4];
    const int b = blockIdx.x;
    const int t = threadIdx.x;

    {
        const float4* __restrict__ anr =
            (const float4*)(assign_norm + ((size_t)b * NATOMS + t) * NC);
#pragma unroll
        for (int i = 0; i < 4; ++i) {
            const float4 v = anr[i];
            an_l[t][4 * i + 0] = v.x; an_l[t][4 * i + 1] = v.y;
            an_l[t][4 * i + 2] = v.z; an_l[t][4 * i + 3] = v.w;
        }
    }
    if (t < 48) xs[t / 3][t % 3] = cg_xyz[(size_t)b * NC * 3 + t];

    float dx0, dx1, dx2;
    {
        const size_t s0 = (((size_t)0 * NB + b) * NATOMS + t) * 3;
        const size_t s1 = (((size_t)1 * NB + b) * NATOMS + t) * 3;
        const size_t s2 = (((size_t)2 * NB + b) * NATOMS + t) * 3;
        const size_t s3 = (((size_t)3 * NB + b) * NATOMS + t) * 3;
        dx0 = (dxp[s0 + 0] + dxp[s1 + 0]) + (dxp[s2 + 0] + dxp[s3 + 0]);
        dx1 = (dxp[s0 + 1] + dxp[s1 + 1]) + (dxp[s2 + 1] + dxp[s3 + 1]);
        dx2 = (dxp[s0 + 2] + dxp[s1 + 2]) + (dxp[s2 + 2] + dxp[s3 + 2]);
    }
    dxl[t][0] = dx0; dxl[t][1] = dx1; dxl[t][2] = dx2;
    __syncthreads();

    {
        const int j = t >> 5, g = t & 31;
        float p0 = 0.f, p1 = 0.f, p2 = 0.f;
#pragma unroll
        for (int k = 0; k < 16; ++k) {
            const int i = g + 32 * k;
            const float a = an_l[i][j];
            p0 += a * dxl[i][0];
            p1 += a * dxl[i][1];
            p2 += a * dxl[i][2];
        }
#pragma unroll
        for (int sh = 1; sh < 32; sh <<= 1) {
            p0 += __shfl_xor(p0, sh);
            p1 += __shfl_xor(p1, sh);
            p2 += __shfl_xor(p2, sh);
        }
        if (g == 0) { cgo_l[j][0] = p0; cgo_l[j][1] = p1; cgo_l[j][2] = p2; }
    }
    __syncthreads();

    const int ci = assign_idx[t];
    const float r0 = xs[ci][0] - cgo_l[ci][0] + dx0;
    const float r1 = xs[ci][1] - cgo_l[ci][1] + dx1;
    const float r2 = xs[ci][2] - cgo_l[ci][2] + dx2;
    const size_t ob = ((size_t)b * NATOMS + t) * 3;
    out_recon[ob + 0] = r0;
    out_recon[ob + 1] = r1;
    out_recon[ob + 2] = r2;
}

extern "C" void kernel_launch(void* const* d_in, const int* in_sizes, int n_in,
                              void* d_out, int out_size, void* d_ws, size_t ws_size,
                              hipStream_t stream) {
    (void)in_sizes; (void)n_in; (void)out_size; (void)ws_size;
    const float* soft_assign = (const float*)d_in[0];
    const float* xyz         = (const float*)d_in[1];
    const float* cg_xyz      = (const float*)d_in[2];
    const float* assign_norm = (const float*)d_in[3];
    const float* W           = (const float*)d_in[4];
    const int*   assign_idx  = (const int*)d_in[5];

    float* out       = (float*)d_out;
    float* out_sa    = out;                                   // 128*512*16
    float* out_xyz   = out + (size_t)NB * NATOMS * NC;        // 128*512*3
    float* out_recon = out_xyz + (size_t)NB * NATOMS * 3;

    float* wcd = (float*)d_ws;                                // 512*256
    float* w1c = wcd + (size_t)NATOMS * NP;                   // 512*16
    float* dxp = w1c + (size_t)NATOMS * NC;                   // 4*128*512*3

    k_stream<<<dim3(NATOMS), dim3(256), 0, stream>>>(W, soft_assign, xyz,
                                                     wcd, w1c, out_sa, out_xyz);
    k_dx<<<dim3(NB * 4), dim3(256), 0, stream>>>(cg_xyz, wcd, w1c, dxp);
    k_finish<<<dim3(NB), dim3(512), 0, stream>>>(cg_xyz, assign_norm, assign_idx,
                                                 dxp, out_recon);
}